// Round 12
// baseline (461.230 us; speedup 1.0000x reference)
//
#include <hip/hip_runtime.h>
#include <stdint.h>

typedef unsigned short u16;
typedef unsigned int   u32;
typedef unsigned long long u64;
typedef __attribute__((ext_vector_type(8))) short bf16x8;
typedef __attribute__((ext_vector_type(4))) float f32x4;

#define NN 20000
#define NE 320000
#define HD 256
#define BD 64

// ws layout (bytes) — total ~24.4 MB
#define WS_PRE   0u           // bf16 [NN][512]                20,480,000
#define WS_W1T   20480000u    // bf16 [3][512][256]               786,432
#define WS_W2T   21266432u    // bf16 [3][256 col][256 k]         393,216
#define WS_PW1   21659648u    // bf16 [128][256]                   65,536
#define WS_PW2   21725184u    // bf16 [32][128]                     8,192
#define WS_PREB  21733376u    // f32  [3][5][256]                  15,360
#define WS_GATE  21748736u    // f32  [15]
#define WS_POOL  21748800u    // f32  [256]
#define WS_FGV   21749824u    // f32  [64]
#define WS_CNT   21750080u    // int  [NN]                         80,000
#define WS_META  21830080u    // int2 [NE] sorted {row|bt<<20,col} 2,560,000

__device__ __forceinline__ u16 f2bf(float f){
  u32 u = __float_as_uint(f);
  u += 0x7fffu + ((u >> 16) & 1u);
  return (u16)(u >> 16);
}
__device__ __forceinline__ u32 pk2(float a, float b){
  return (u32)f2bf(a) | ((u32)f2bf(b) << 16);
}
__device__ __forceinline__ float bf2f(u16 u){
  return __uint_as_float((u32)u << 16);
}
// truncating bf16 pack: low16 = trunc(a), high16 = trunc(b) — 1 VALU op
__device__ __forceinline__ u32 pk2t(float a, float b){
  return __builtin_amdgcn_perm(__float_as_uint(a), __float_as_uint(b), 0x03020706u);
}
// two bf16 pairs -> relu(a+b+p) -> packed bf16 (truncated)
__device__ __forceinline__ u32 relu_pack(u32 a, u32 b, float p0, float p1){
  float a0 = __uint_as_float(a << 16);
  float a1 = __uint_as_float(a & 0xffff0000u);
  float b0 = __uint_as_float(b << 16);
  float b1 = __uint_as_float(b & 0xffff0000u);
  float s0 = fmaxf(a0 + b0 + p0, 0.f);
  float s1 = fmaxf(a1 + b1 + p1, 0.f);
  return pk2t(s0, s1);
}

// ---- merged one-time setup (read-coalesced transposes) ----
__global__ void setup_k(const float* __restrict__ gw1,
                        const float* __restrict__ gw2,
                        const float* __restrict__ pw1,
                        const float* __restrict__ pw2,
                        const float* __restrict__ bond_table,
                        const float* __restrict__ gb1,
                        const float* __restrict__ att_w,
                        const float* __restrict__ att_b,
                        const float* __restrict__ x,
                        const float* __restrict__ atom_table,
                        const float* __restrict__ charge_table,
                        const float* __restrict__ hybrid_table,
                        u16* __restrict__ w1t, u16* __restrict__ w2t,
                        u16* __restrict__ pw1bf, u16* __restrict__ pw2bf,
                        float* __restrict__ preb,
                        float* __restrict__ gate_tab, float* __restrict__ pooled,
                        int* __restrict__ cnt,
                        float* __restrict__ h0, float* __restrict__ out_at){
  int i = blockIdx.x*256 + threadIdx.x;
  if (i < 442368){
    float v = gw1[i];
    int l = i / 147456;
    int r = i - l*147456;
    int srow = r >> 8, c = r & 255;
    if (srow < 512){
      int dc = (srow < 256) ? c : (256 + c);
      w1t[((size_t)l*512 + dc)*256 + (srow & 255)] = f2bf(v);
    }
  } else if (i < 638976){
    // coalesced read of gw2, plain transpose w2t[l][col][k]
    int t = i - 442368;
    float v = gw2[t];
    int l = t >> 16;
    int k = (t >> 8) & 255;
    int c = t & 255;
    w2t[(((size_t)l*256 + c) << 8) | k] = f2bf(v);
  } else if (i < 671744){
    int t = i - 638976;
    float v = pw1[t];
    int k = t >> 7, o = t & 127;
    pw1bf[o*256 + k] = f2bf(v);
  } else if (i < 675840){
    int t = i - 671744;
    float v = pw2[t];
    int k = t >> 5, o = t & 31;
    pw2bf[o*128 + k] = f2bf(v);
  } else if (i < 679680){
    int t = i - 675840;
    int l = t / 1280;
    int r = t - l*1280;
    int bt = r >> 8, c = r & 255;
    float s = gb1[l*HD + c];
    for (int d = 0; d < BD; ++d)
      s += bond_table[bt*BD + d] * gw1[(l*576 + 512 + d)*256 + c];
    preb[(l*5 + bt)*256 + c] = s;
  } else if (i < 679695){
    int t = i - 679680;
    int l = t / 5, b = t - 5*l;
    float s = att_b[l];
    for (int d = 0; d < BD; ++d) s += bond_table[b*BD + d] * att_w[l*BD + d];
    gate_tab[t] = 1.0f / (1.0f + __expf(-s));
  } else if (i < 679951){
    pooled[i - 679695] = 0.0f;
  } else if (i < 699951){
    cnt[i - 679951] = 0;
  } else if (i < 1339951){
    int t = i - 699951;
    int n = t >> 5, sub = t & 31, c0 = sub*8;
    int at = (int)x[n*3 + 0]; at = at < 0 ? 0 : (at > 10 ? 10 : at);
    float4 v0 = {0.f,0.f,0.f,0.f}, v1 = {0.f,0.f,0.f,0.f};
    if (c0 < 64){
      v0 = *(const float4*)(atom_table + at*64 + c0);
      v1 = *(const float4*)(atom_table + at*64 + c0 + 4);
    } else if (c0 < 96){
      int fc = (int)x[n*3 + 2] + 3; fc = fc < 0 ? 0 : (fc > 6 ? 6 : fc);
      v0 = *(const float4*)(charge_table + fc*32 + (c0 - 64));
      v1 = *(const float4*)(charge_table + fc*32 + (c0 - 64) + 4);
    } else if (c0 < 128){
      int hy = (int)x[n*3 + 1]; hy = hy < 0 ? 0 : (hy > 7 ? 7 : hy);
      v0 = *(const float4*)(hybrid_table + hy*32 + (c0 - 96));
      v1 = *(const float4*)(hybrid_table + hy*32 + (c0 - 96) + 4);
    }
    *(float4*)(h0 + (size_t)n*HD + c0)     = v0;
    *(float4*)(h0 + (size_t)n*HD + c0 + 4) = v1;
    if (sub == 0) out_at[n] = (float)at;
  }
}

// ---- counting sort by row ----
__global__ void hist_k(const int* __restrict__ eidx, int* __restrict__ cnt){
  int e = blockIdx.x*256 + threadIdx.x;
  int r = eidx[e]; r = r < 0 ? 0 : (r >= NN ? NN-1 : r);
  atomicAdd(&cnt[r], 1);
}

__launch_bounds__(1024)
__global__ void scan_k(int* __restrict__ cnt){
  __shared__ int part[1024];
  int t = threadIdx.x;
  int base = t*20;
  int loc[20];
  int s = 0;
  #pragma unroll
  for (int j = 0; j < 20; ++j){
    int idx = base + j;
    int v = (idx < NN) ? cnt[idx] : 0;
    loc[j] = v; s += v;
  }
  part[t] = s; __syncthreads();
  for (int off = 1; off < 1024; off <<= 1){
    int v = (t >= off) ? part[t-off] : 0;
    __syncthreads();
    part[t] += v;
    __syncthreads();
  }
  int run = part[t] - s;
  #pragma unroll
  for (int j = 0; j < 20; ++j){
    int idx = base + j;
    if (idx < NN){ cnt[idx] = run; run += loc[j]; }
  }
}

__global__ void scatter_k(const int* __restrict__ eidx,
                          const float* __restrict__ eattr,
                          int* __restrict__ cur,
                          int2* __restrict__ smeta){
  int e = blockIdx.x*256 + threadIdx.x;
  int r = eidx[e];        r = r < 0 ? 0 : (r >= NN ? NN-1 : r);
  int c = eidx[NE + e];   c = c < 0 ? 0 : (c >= NN ? NN-1 : c);
  int bt = (int)eattr[e]; bt = bt < 0 ? 0 : (bt > 4 ? 4 : bt);
  int pos = atomicAdd(&cur[r], 1);
  if (pos >= 0 && pos < NE){
    int2 m; m.x = r | (bt << 20); m.y = c;
    smeta[pos] = m;
  }
}

// ---- pre = bf16( h @ [W1a|W1b] ) : [NN][512], two passes via grid.y ----
__launch_bounds__(256, 4)
__global__ void pre_k(const float* __restrict__ h,
                      const u16* __restrict__ w1t,
                      u16* __restrict__ pre, int layer){
  __shared__ u16 a_lds[64*40];
  __shared__ u16 b_lds[256*40];
  const int tid = threadIdx.x;
  const int n0 = blockIdx.x * 64;
  const int half = blockIdx.y;
  const int w = tid >> 6, lane = tid & 63, g = lane >> 4, lr = lane & 15;
  const int rstage = tid >> 2, q = tid & 3;
  int arow = n0 + rstage; if (arow >= NN) arow = NN-1;
  const float* hrow = h + (size_t)arow*HD;
  const u16* bp = w1t + ((size_t)layer*512 + (size_t)half*256 + tid)*256;

  f32x4 acc[4][4];
  for (int mi = 0; mi < 4; ++mi)
    for (int nj = 0; nj < 4; ++nj)
      acc[mi][nj] = (f32x4){0.f,0.f,0.f,0.f};

  for (int ks = 0; ks < 8; ++ks){
    __syncthreads();
    {
      const float* src = hrow + ks*32 + q*8;
      float4 f0 = *(const float4*)src;
      float4 f1 = *(const float4*)(src + 4);
      uint4 av;
      av.x = pk2(f0.x,f0.y); av.y = pk2(f0.z,f0.w);
      av.z = pk2(f1.x,f1.y); av.w = pk2(f1.z,f1.w);
      *(uint4*)(a_lds + rstage*40 + q*8) = av;
    }
    {
      const u16* src = bp + ks*32;
      uint4 s0 = *(const uint4*)(src);
      uint4 s1 = *(const uint4*)(src + 8);
      uint4 s2 = *(const uint4*)(src + 16);
      uint4 s3 = *(const uint4*)(src + 24);
      u16* dst = b_lds + tid*40;
      *(uint4*)(dst)      = s0;
      *(uint4*)(dst + 8)  = s1;
      *(uint4*)(dst + 16) = s2;
      *(uint4*)(dst + 24) = s3;
    }
    __syncthreads();
    bf16x8 af[4], bfr[4];
    for (int mi = 0; mi < 4; ++mi)
      af[mi] = *(const bf16x8*)(a_lds + (mi*16 + lr)*40 + g*8);
    for (int nj = 0; nj < 4; ++nj)
      bfr[nj] = *(const bf16x8*)(b_lds + (w*64 + nj*16 + lr)*40 + g*8);
    for (int mi = 0; mi < 4; ++mi)
      for (int nj = 0; nj < 4; ++nj)
        acc[mi][nj] = __builtin_amdgcn_mfma_f32_16x16x32_bf16(af[mi], bfr[nj], acc[mi][nj], 0, 0, 0);
  }

  for (int mi = 0; mi < 4; ++mi)
    for (int nj = 0; nj < 4; ++nj)
      for (int p = 0; p < 4; ++p){
        int re = mi*16 + g*4 + p;
        int n = n0 + re;
        if (n < NN)
          pre[(size_t)n*512 + half*256 + w*64 + nj*16 + lr] = f2bf(acc[mi][nj][p]);
      }
}

// ---- fused edge kernel: persistent blocks, W2 slice resident in registers,
//      contiguous per-XCD tile chunks, pure LDS+MFMA k-loop ----
__launch_bounds__(512, 4)
__global__ void edge_msg_k(const int2* __restrict__ smeta,
                           const u16* __restrict__ pre,
                           const float* __restrict__ prebg,
                           const u16* __restrict__ w2t,
                           const float* __restrict__ b2g,
                           const float* __restrict__ gate_tab,
                           float* __restrict__ h,
                           int layer){
  __shared__ u16 t_lds[64*264];    // 33792B  t matrix
  __shared__ u16 m_lds[16384];     // 32768B  msg transpose buffer
  __shared__ int   row_l[64];
  __shared__ float gate_l[64];
  __shared__ u64   mask_l;

  const int tid = threadIdx.x;
  const int w = tid >> 6, lane = tid & 63, g = lane >> 4, lr = lane & 15;
  const int rstage = tid >> 3, q = tid & 7;

  // ---- persistent W2 slice in registers: wave w owns cols w*32..w*32+31 ----
  // 16 x bf16x8 = 64 VGPRs, statically indexed (rule #20), loaded ONCE per block
  const u16* w2base = w2t + (size_t)layer*65536;
  bf16x8 Bf[8][2];
  #pragma unroll
  for (int ks = 0; ks < 8; ++ks)
    #pragma unroll
    for (int nj = 0; nj < 2; ++nj)
      Bf[ks][nj] = *(const bf16x8*)(w2base + (size_t)(w*32 + nj*16 + lr)*256 + ks*32 + g*8);

  float b2v[2];
  #pragma unroll
  for (int nj = 0; nj < 2; ++nj) b2v[nj] = b2g[layer*HD + w*32 + nj*16 + lr];

  // ---- block -> contiguous tile chunk within its XCD range (5000 tiles = 8 x 625) ----
  const int bidv = blockIdx.x;           // 512 blocks = 2/CU, exactly co-resident
  const int xcd = bidv & 7, idx = bidv >> 3;   // idx 0..63, 64 blocks per XCD
  int tstart, tcnt;
  if (idx < 49){ tstart = xcd*625 + idx*10;           tcnt = 10; }
  else         { tstart = xcd*625 + 490 + (idx-49)*9; tcnt = 9;  }

  for (int t = 0; t < tcnt; ++t){
    const int eBase = (tstart + t)*64;
    if (t) __syncthreads();      // prior tile's reduce done before meta/t_lds overwrite

    // one-load edge metadata
    int2 m0 = smeta[eBase + rstage];
    const int rI  = m0.x & 0xFFFFF;
    const int btI = (m0.x >> 20) & 7;
    const int cI  = m0.y;

    if (tid < 64){
      int2 mm = smeta[eBase + tid];
      int r = mm.x & 0xFFFFF;
      row_l[tid] = r;
      gate_l[tid] = gate_tab[layer*5 + ((mm.x >> 20) & 7)];
      int rprev = __shfl_up(r, 1);
      bool fl = (tid > 0) && (r != rprev);
      u64 mk = __ballot(fl);
      if (tid == 0) mask_l = mk;
    }

    // ---- t = relu(pre1[row] + pre2[col] + preb[bt]) -> bf16 t_lds ----
    {
      const u16* p1 = pre + (size_t)rI*512;
      const u16* p2 = pre + (size_t)cI*512 + 256;
      const float* pb = prebg + (size_t)(layer*5 + btI)*256;
      uint4 v1[4], v2[4];
      #pragma unroll
      for (int it = 0; it < 4; ++it){
        int c0 = it*64 + q*8;
        v1[it] = *(const uint4*)(p1 + c0);
        v2[it] = *(const uint4*)(p2 + c0);
      }
      #pragma unroll
      for (int it = 0; it < 4; ++it){
        int c0 = it*64 + q*8;
        float4 pa = *(const float4*)(pb + c0);
        float4 pc = *(const float4*)(pb + c0 + 4);
        uint4 ov;
        ov.x = relu_pack(v1[it].x, v2[it].x, pa.x, pa.y);
        ov.y = relu_pack(v1[it].y, v2[it].y, pa.z, pa.w);
        ov.z = relu_pack(v1[it].z, v2[it].z, pc.x, pc.y);
        ov.w = relu_pack(v1[it].w, v2[it].w, pc.z, pc.w);
        *(uint4*)(t_lds + rstage*264 + c0) = ov;
      }
    }

    __syncthreads();   // t_lds + row_l/gate_l/mask_l visible to all waves

    f32x4 acc[4][2];
    for (int mi = 0; mi < 4; ++mi)
      for (int nj = 0; nj < 2; ++nj)
        acc[mi][nj] = (f32x4){0.f,0.f,0.f,0.f};

    // ---- GEMM2: pure LDS-read + MFMA, B operands already in registers ----
    #pragma unroll
    for (int ks = 0; ks < 8; ++ks){
      bf16x8 af[4];
      #pragma unroll
      for (int mi = 0; mi < 4; ++mi)
        af[mi] = *(const bf16x8*)(t_lds + (mi*16 + lr)*264 + ks*32 + g*8);
      __builtin_amdgcn_s_setprio(1);
      #pragma unroll
      for (int mi = 0; mi < 4; ++mi){
        acc[mi][0] = __builtin_amdgcn_mfma_f32_16x16x32_bf16(af[mi], Bf[ks][0], acc[mi][0], 0, 0, 0);
        acc[mi][1] = __builtin_amdgcn_mfma_f32_16x16x32_bf16(af[mi], Bf[ks][1], acc[mi][1], 0, 0, 0);
      }
      __builtin_amdgcn_s_setprio(0);
    }

    // ---- epilogue: (+b2)*gate -> bf16 msgs into m_lds ----
    {
      for (int mi = 0; mi < 4; ++mi)
        for (int nj = 0; nj < 2; ++nj){
          u16* mb = m_lds + nj*8192 + w*1024 + lr*64;
          float v[4];
          #pragma unroll
          for (int p = 0; p < 4; ++p){
            int re = mi*16 + g*4 + p;
            v[p] = (acc[mi][nj][p] + b2v[nj]) * gate_l[re];
          }
          int slot = (mi*2 + (g >> 1)) ^ (lr & 7);
          uint2 pkv; pkv.x = pk2t(v[0], v[1]); pkv.y = pk2t(v[2], v[3]);
          *(uint2*)(mb + slot*8 + (g & 1)*4) = pkv;
        }
    }
    __syncthreads();

    // ---- segmented reduction: wave-uniform mask flush ----
    {
      const int cl = tid & 255, half = tid >> 8;   // half uniform per wave
      u64 mk = mask_l;
      u32 m32 = (u32)(mk >> (half ? 32 : 0));
      m32 = __builtin_amdgcn_readfirstlane(m32);
      const u16* mb = m_lds + ((cl >> 4) & 1)*8192 + (cl >> 5)*1024 + (cl & 15)*64;
      float run = 0.f;
      #pragma unroll
      for (int e8l = 0; e8l < 4; ++e8l){
        int e8 = half*4 + e8l;
        bf16x8 mv = *(const bf16x8*)(mb + ((e8 ^ (cl & 7)) << 3));
        #pragma unroll
        for (int j = 0; j < 8; ++j){
          int el = e8l*8 + j;              // local edge 0..31
          run += bf2f((u16)mv[j]);
          bool fl = (el == 31) || ((m32 >> (el + 1)) & 1u);
          if (fl){
            int rr = row_l[half*32 + el];
            atomicAdd(h + (size_t)rr*HD + cl, run);
            run = 0.f;
          }
        }
      }
    }
  }
}

// ---- column sums for pooling ----
__global__ void pool_k(const float* __restrict__ h,
                       float* __restrict__ pooled){
  int c = threadIdx.x;
  int r0 = blockIdx.x * 50;
  float s = 0.f;
  for (int r = r0; r < r0 + 50; ++r)
    s += h[(size_t)r*HD + c];
  atomicAdd(&pooled[c], s);
}

// ---- fg = mean(h) @ fg_w + fg_b (computed once) ----
__global__ void fg_k(const float* __restrict__ pooled,
                     const float* __restrict__ fg_w,
                     const float* __restrict__ fg_b,
                     float* __restrict__ fg_vals){
  int o = threadIdx.x;
  int k = o >> 4, j = o & 15;
  float s = 0.f;
  for (int d = 0; d < HD; ++d) s += pooled[d] * fg_w[(size_t)k*HD*16 + d*16 + j];
  fg_vals[o] = s / (float)NN + fg_b[k*16 + j];
}

__global__ void bcast_fg_k(const float* __restrict__ fg_vals,
                           float* __restrict__ out_fg){
  __shared__ float fv[64];
  if (threadIdx.x < 64) fv[threadIdx.x] = fg_vals[threadIdx.x];
  __syncthreads();
  int i = blockIdx.x*256 + threadIdx.x;
  out_fg[i] = fv[i & 63];
}

// ---- chemical properties MLP, both layers via MFMA ----
__launch_bounds__(256, 3)
__global__ void props_mfma_k(const float* __restrict__ h,
                             const u16* __restrict__ pw1bf,
                             const float* __restrict__ pb1,
                             const u16* __restrict__ pw2bf,
                             const float* __restrict__ pb2,
                             float* __restrict__ outp){
  __shared__ u16 a_lds[64*40];
  __shared__ u16 b2_lds[128*40];   // k-loop W1 staging; then pw2 [32][k128] stride 136
  __shared__ u16 t2[64*136];
  const int tid = threadIdx.x;
  const int n0 = blockIdx.x*64;
  const int w = tid >> 6, lane = tid & 63, g = lane >> 4, lr = lane & 15;
  const int rstage = tid >> 2, q = tid & 3;
  int arow = n0 + rstage; if (arow >= NN) arow = NN-1;
  const float* hrow = h + (size_t)arow*HD;

  const int colb = tid >> 1, halfb = tid & 1;

  f32x4 acc[4][2];
  for (int mi = 0; mi < 4; ++mi)
    for (int nj = 0; nj < 2; ++nj)
      acc[mi][nj] = (f32x4){0.f,0.f,0.f,0.f};

  for (int ks = 0; ks < 8; ++ks){
    __syncthreads();
    {
      const float* src = hrow + ks*32 + q*8;
      float4 f0 = *(const float4*)src;
      float4 f1 = *(const float4*)(src + 4);
      uint4 av;
      av.x = pk2(f0.x,f0.y); av.y = pk2(f0.z,f0.w);
      av.z = pk2(f1.x,f1.y); av.w = pk2(f1.z,f1.w);
      *(uint4*)(a_lds + rstage*40 + q*8) = av;
    }
    {
      const u16* src = pw1bf + colb*256 + ks*32 + halfb*16;
      uint4 s0 = *(const uint4*)src;
      uint4 s1 = *(const uint4*)(src + 8);
      u16* dst = b2_lds + colb*40 + halfb*16;
      *(uint4*)dst = s0; *(uint4*)(dst + 8) = s1;
    }
    __syncthreads();
    bf16x8 af[4], bfr[2];
    for (int mi = 0; mi < 4; ++mi)
      af[mi] = *(const bf16x8*)(a_lds + (mi*16 + lr)*40 + g*8);
    for (int nj = 0; nj < 2; ++nj)
      bfr[nj] = *(const bf16x8*)(b2_lds + (w*32 + nj*16 + lr)*40 + g*8);
    for (int mi = 0; mi < 4; ++mi)
      for (int nj = 0; nj < 2; ++nj)
        acc[mi][nj] = __builtin_amdgcn_mfma_f32_16x16x32_bf16(af[mi], bfr[nj], acc[mi][nj], 0, 0, 0);
  }

  // bias + relu -> t2 (bf16)
  {
    float b1v[2];
    for (int nj = 0; nj < 2; ++nj) b1v[nj] = pb1[w*32 + nj*16 + lr];
    for (int mi = 0; mi < 4; ++mi)
      for (int nj = 0; nj < 2; ++nj){
        int colt = w*32 + nj*16 + lr;
        for (int p = 0; p < 4; ++p){
          float v = acc[mi][nj][p] + b1v[nj];
          v = v > 0.f ? v : 0.f;
          t2[(mi*16 + g*4 + p)*136 + colt] = f2bf(v);
        }
      }
  }
  __syncthreads();   // t2 complete; b2_lds reads from k-loop done

  // stage pw2bf [32 cols][128 k] into b2_lds at stride 136
  {
    int col = tid >> 3, part = tid & 7;
    const u16* src = pw2bf + col*128 + part*16;
    u16* dst = b2_lds + col*136 + part*16;
    *(uint4*)dst       = *(const uint4*)src;
    *(uint4*)(dst + 8) = *(const uint4*)(src + 8);
  }
  __syncthreads();

  // phase 2 via MFMA: [64x128] @ [128x32]; wave w owns rows w*16..w*16+15
  {
    f32x4 acc2[2];
    for (int nj = 0; nj < 2; ++nj) acc2[nj] = (f32x4){0.f,0.f,0.f,0.f};
    for (int ks = 0; ks < 4; ++ks){
      bf16x8 af = *(const bf16x8*)(t2 + (w*16 + lr)*136 + ks*32 + g*8);
      for (int nj = 0; nj < 2; ++nj){
        bf16x8 bf = *(const bf16x8*)(b2_lds + (nj*16 + lr)*136 + ks*32 + g*8);
        acc2[nj] = __builtin_amdgcn_mfma_f32_16x16x32_bf16(af, bf, acc2[nj], 0, 0, 0);
      }
    }
    for (int nj = 0; nj < 2; ++nj)
      for (int p = 0; p < 4; ++p){
        int n = n0 + w*16 + g*4 + p;
        int col = nj*16 + lr;
        if (n < NN)
          outp[(size_t)n*32 + col] = acc2[nj][p] + pb2[col];
      }
  }
}

extern "C" void kernel_launch(void* const* d_in, const int* in_sizes, int n_in,
                              void* d_out, int out_size, void* d_ws, size_t ws_size,
                              hipStream_t stream) {
  const float* x            = (const float*)d_in[0];
  const int*   eidx         = (const int*)  d_in[1];
  const float* eattr        = (const float*)d_in[2];
  const float* atom_table   = (const float*)d_in[4];
  const float* charge_table = (const float*)d_in[5];
  const float* hybrid_table = (const float*)d_in[6];
  const float* bond_table   = (const float*)d_in[7];
  const float* gw1          = (const float*)d_in[8];
  const float* gb1          = (const float*)d_in[9];
  const float* gw2          = (const float*)d_in[10];
  const float* gb2          = (const float*)d_in[11];
  const float* attw         = (const float*)d_in[12];
  const float* attb         = (const float*)d_in[13];
  const float* pw1          = (const float*)d_in[14];
  const float* pb1          = (const float*)d_in[15];
  const float* pw2          = (const float*)d_in[16];
  const float* pb2          = (const float*)d_in[17];
  const float* fgw          = (const float*)d_in[18];
  const float* fgb          = (const float*)d_in[19];

  float* out       = (float*)d_out;
  float* out_h     = out;
  float* out_props = out + (size_t)NN*HD;
  float* out_fg    = out_props + (size_t)NN*32;
  float* out_at    = out_fg + (size_t)NN*64;

  char* ws = (char*)d_ws;
  u16*   pre      = (u16*)  (ws + WS_PRE);
  u16*   w1t      = (u16*)  (ws + WS_W1T);
  u16*   w2t      = (u16*)  (ws + WS_W2T);
  u16*   pw1bf    = (u16*)  (ws + WS_PW1);
  u16*   pw2bf    = (u16*)  (ws + WS_PW2);
  float* prebg    = (float*)(ws + WS_PREB);
  float* gate_tab = (float*)(ws + WS_GATE);
  float* pooled   = (float*)(ws + WS_POOL);
  float* fg_vals  = (float*)(ws + WS_FGV);
  int*   cnt      = (int*)  (ws + WS_CNT);
  int2*  smeta    = (int2*) (ws + WS_META);

  setup_k<<<5235, 256, 0, stream>>>(gw1, gw2, pw1, pw2, bond_table, gb1, attw, attb,
                                    x, atom_table, charge_table, hybrid_table,
                                    w1t, w2t, pw1bf, pw2bf, prebg, gate_tab, pooled,
                                    cnt, out_h, out_at);

  hist_k<<<1250, 256, 0, stream>>>(eidx, cnt);
  scan_k<<<1, 1024, 0, stream>>>(cnt);
  scatter_k<<<1250, 256, 0, stream>>>(eidx, eattr, cnt, smeta);

  for (int l = 0; l < 3; ++l){
    pre_k<<<dim3(313, 2), 256, 0, stream>>>(out_h, w1t, pre, l);
    edge_msg_k<<<512, 512, 0, stream>>>(smeta, pre, prebg, w2t,
                                        gb2, gate_tab, out_h, l);
  }

  pool_k<<<400, 256, 0, stream>>>(out_h, pooled);
  fg_k<<<1, 64, 0, stream>>>(pooled, fgw, fgb, fg_vals);
  props_mfma_k<<<313, 256, 0, stream>>>(out_h, pw1bf, pb1, pw2bf, pb2, out_props);
  bcast_fg_k<<<5000, 256, 0, stream>>>(fg_vals, out_fg);
}

// Round 13
// 376.616 us; speedup vs baseline: 1.2247x; 1.2247x over previous
//
#include <hip/hip_runtime.h>
#include <stdint.h>

typedef unsigned short u16;
typedef unsigned int   u32;
typedef unsigned long long u64;
typedef __attribute__((ext_vector_type(8))) short bf16x8;
typedef __attribute__((ext_vector_type(4))) float f32x4;

#define NN 20000
#define NE 320000
#define HD 256
#define BD 64

// ws layout (bytes) — total ~24.4 MB
#define WS_PRE   0u           // bf16 [NN][512]                20,480,000
#define WS_W1T   20480000u    // bf16 [3][512][256]               786,432
#define WS_W2I   21266432u    // bf16 W2 swizzled image           393,216
#define WS_PW1   21659648u    // bf16 [128][256]                   65,536
#define WS_PW2   21725184u    // bf16 [32][128]                     8,192
#define WS_PREB  21733376u    // f32  [3][5][256]                  15,360
#define WS_GATE  21748736u    // f32  [15]
#define WS_POOL  21748800u    // f32  [256]
#define WS_FGV   21749824u    // f32  [64]
#define WS_CNT   21750080u    // int  [NN]                         80,000
#define WS_META  21830080u    // int2 [NE] sorted {row|bt<<20,col} 2,560,000

__device__ __forceinline__ u16 f2bf(float f){
  u32 u = __float_as_uint(f);
  u += 0x7fffu + ((u >> 16) & 1u);
  return (u16)(u >> 16);
}
__device__ __forceinline__ u32 pk2(float a, float b){
  return (u32)f2bf(a) | ((u32)f2bf(b) << 16);
}
__device__ __forceinline__ float bf2f(u16 u){
  return __uint_as_float((u32)u << 16);
}
// truncating bf16 pack: low16 = trunc(a), high16 = trunc(b) — 1 VALU op
__device__ __forceinline__ u32 pk2t(float a, float b){
  return __builtin_amdgcn_perm(__float_as_uint(a), __float_as_uint(b), 0x03020706u);
}
// two bf16 pairs -> relu(a+b+p) -> packed bf16 (truncated)
__device__ __forceinline__ u32 relu_pack(u32 a, u32 b, float p0, float p1){
  float a0 = __uint_as_float(a << 16);
  float a1 = __uint_as_float(a & 0xffff0000u);
  float b0 = __uint_as_float(b << 16);
  float b1 = __uint_as_float(b & 0xffff0000u);
  float s0 = fmaxf(a0 + b0 + p0, 0.f);
  float s1 = fmaxf(a1 + b1 + p1, 0.f);
  return pk2t(s0, s1);
}
__device__ __forceinline__ void gl_lds16(const u16* g, u16* l){
  __builtin_amdgcn_global_load_lds(
      (const __attribute__((address_space(1))) unsigned int*)g,
      (__attribute__((address_space(3))) unsigned int*)l, 16, 0, 0);
}

// ---- merged one-time setup (read-coalesced transposes) ----
__global__ void setup_k(const float* __restrict__ gw1,
                        const float* __restrict__ gw2,
                        const float* __restrict__ pw1,
                        const float* __restrict__ pw2,
                        const float* __restrict__ bond_table,
                        const float* __restrict__ gb1,
                        const float* __restrict__ att_w,
                        const float* __restrict__ att_b,
                        const float* __restrict__ x,
                        const float* __restrict__ atom_table,
                        const float* __restrict__ charge_table,
                        const float* __restrict__ hybrid_table,
                        u16* __restrict__ w1t, u16* __restrict__ w2img,
                        u16* __restrict__ pw1bf, u16* __restrict__ pw2bf,
                        float* __restrict__ preb,
                        float* __restrict__ gate_tab, float* __restrict__ pooled,
                        int* __restrict__ cnt,
                        float* __restrict__ h0, float* __restrict__ out_at){
  int i = blockIdx.x*256 + threadIdx.x;
  if (i < 442368){
    float v = gw1[i];
    int l = i / 147456;
    int r = i - l*147456;
    int srow = r >> 8, c = r & 255;
    if (srow < 512){
      int dc = (srow < 256) ? c : (256 + c);
      w1t[((size_t)l*512 + dc)*256 + (srow & 255)] = f2bf(v);
    }
  } else if (i < 638976){
    int t = i - 442368;
    float v = gw2[t];
    int l = t >> 16;
    int rest = t & 65535;
    int k = rest >> 8, c = rest & 255;
    int ks = k >> 5, k5 = k & 31;
    int kc = k5 >> 3, j = k5 & 7;
    int s = kc ^ ((c >> 1) & 3);
    w2img[(((l*8 + ks)*256 + c)*4 + s)*8 + j] = f2bf(v);
  } else if (i < 671744){
    int t = i - 638976;
    float v = pw1[t];
    int k = t >> 7, o = t & 127;
    pw1bf[o*256 + k] = f2bf(v);
  } else if (i < 675840){
    int t = i - 671744;
    float v = pw2[t];
    int k = t >> 5, o = t & 31;
    pw2bf[o*128 + k] = f2bf(v);
  } else if (i < 679680){
    int t = i - 675840;
    int l = t / 1280;
    int r = t - l*1280;
    int bt = r >> 8, c = r & 255;
    float s = gb1[l*HD + c];
    for (int d = 0; d < BD; ++d)
      s += bond_table[bt*BD + d] * gw1[(l*576 + 512 + d)*256 + c];
    preb[(l*5 + bt)*256 + c] = s;
  } else if (i < 679695){
    int t = i - 679680;
    int l = t / 5, b = t - 5*l;
    float s = att_b[l];
    for (int d = 0; d < BD; ++d) s += bond_table[b*BD + d] * att_w[l*BD + d];
    gate_tab[t] = 1.0f / (1.0f + __expf(-s));
  } else if (i < 679951){
    pooled[i - 679695] = 0.0f;
  } else if (i < 699951){
    cnt[i - 679951] = 0;
  } else if (i < 1339951){
    int t = i - 699951;
    int n = t >> 5, sub = t & 31, c0 = sub*8;
    int at = (int)x[n*3 + 0]; at = at < 0 ? 0 : (at > 10 ? 10 : at);
    float4 v0 = {0.f,0.f,0.f,0.f}, v1 = {0.f,0.f,0.f,0.f};
    if (c0 < 64){
      v0 = *(const float4*)(atom_table + at*64 + c0);
      v1 = *(const float4*)(atom_table + at*64 + c0 + 4);
    } else if (c0 < 96){
      int fc = (int)x[n*3 + 2] + 3; fc = fc < 0 ? 0 : (fc > 6 ? 6 : fc);
      v0 = *(const float4*)(charge_table + fc*32 + (c0 - 64));
      v1 = *(const float4*)(charge_table + fc*32 + (c0 - 64) + 4);
    } else if (c0 < 128){
      int hy = (int)x[n*3 + 1]; hy = hy < 0 ? 0 : (hy > 7 ? 7 : hy);
      v0 = *(const float4*)(hybrid_table + hy*32 + (c0 - 96));
      v1 = *(const float4*)(hybrid_table + hy*32 + (c0 - 96) + 4);
    }
    *(float4*)(h0 + (size_t)n*HD + c0)     = v0;
    *(float4*)(h0 + (size_t)n*HD + c0 + 4) = v1;
    if (sub == 0) out_at[n] = (float)at;
  }
}

// ---- counting sort by row ----
__global__ void hist_k(const int* __restrict__ eidx, int* __restrict__ cnt){
  int e = blockIdx.x*256 + threadIdx.x;
  int r = eidx[e]; r = r < 0 ? 0 : (r >= NN ? NN-1 : r);
  atomicAdd(&cnt[r], 1);
}

__launch_bounds__(1024)
__global__ void scan_k(int* __restrict__ cnt){
  __shared__ int part[1024];
  int t = threadIdx.x;
  int base = t*20;
  int loc[20];
  int s = 0;
  #pragma unroll
  for (int j = 0; j < 20; ++j){
    int idx = base + j;
    int v = (idx < NN) ? cnt[idx] : 0;
    loc[j] = v; s += v;
  }
  part[t] = s; __syncthreads();
  for (int off = 1; off < 1024; off <<= 1){
    int v = (t >= off) ? part[t-off] : 0;
    __syncthreads();
    part[t] += v;
    __syncthreads();
  }
  int run = part[t] - s;
  #pragma unroll
  for (int j = 0; j < 20; ++j){
    int idx = base + j;
    if (idx < NN){ cnt[idx] = run; run += loc[j]; }
  }
}

__global__ void scatter_k(const int* __restrict__ eidx,
                          const float* __restrict__ eattr,
                          int* __restrict__ cur,
                          int2* __restrict__ smeta){
  int e = blockIdx.x*256 + threadIdx.x;
  int r = eidx[e];        r = r < 0 ? 0 : (r >= NN ? NN-1 : r);
  int c = eidx[NE + e];   c = c < 0 ? 0 : (c >= NN ? NN-1 : c);
  int bt = (int)eattr[e]; bt = bt < 0 ? 0 : (bt > 4 ? 4 : bt);
  int pos = atomicAdd(&cur[r], 1);
  if (pos >= 0 && pos < NE){
    int2 m; m.x = r | (bt << 20); m.y = c;
    smeta[pos] = m;
  }
}

// ---- pre = bf16( h @ [W1a|W1b] ) : [NN][512], two passes via grid.y ----
__launch_bounds__(256, 4)
__global__ void pre_k(const float* __restrict__ h,
                      const u16* __restrict__ w1t,
                      u16* __restrict__ pre, int layer){
  __shared__ u16 a_lds[64*40];
  __shared__ u16 b_lds[256*40];
  const int tid = threadIdx.x;
  const int n0 = blockIdx.x * 64;
  const int half = blockIdx.y;
  const int w = tid >> 6, lane = tid & 63, g = lane >> 4, lr = lane & 15;
  const int rstage = tid >> 2, q = tid & 3;
  int arow = n0 + rstage; if (arow >= NN) arow = NN-1;
  const float* hrow = h + (size_t)arow*HD;
  const u16* bp = w1t + ((size_t)layer*512 + (size_t)half*256 + tid)*256;

  f32x4 acc[4][4];
  for (int mi = 0; mi < 4; ++mi)
    for (int nj = 0; nj < 4; ++nj)
      acc[mi][nj] = (f32x4){0.f,0.f,0.f,0.f};

  for (int ks = 0; ks < 8; ++ks){
    __syncthreads();
    {
      const float* src = hrow + ks*32 + q*8;
      float4 f0 = *(const float4*)src;
      float4 f1 = *(const float4*)(src + 4);
      uint4 av;
      av.x = pk2(f0.x,f0.y); av.y = pk2(f0.z,f0.w);
      av.z = pk2(f1.x,f1.y); av.w = pk2(f1.z,f1.w);
      *(uint4*)(a_lds + rstage*40 + q*8) = av;
    }
    {
      const u16* src = bp + ks*32;
      uint4 s0 = *(const uint4*)(src);
      uint4 s1 = *(const uint4*)(src + 8);
      uint4 s2 = *(const uint4*)(src + 16);
      uint4 s3 = *(const uint4*)(src + 24);
      u16* dst = b_lds + tid*40;
      *(uint4*)(dst)      = s0;
      *(uint4*)(dst + 8)  = s1;
      *(uint4*)(dst + 16) = s2;
      *(uint4*)(dst + 24) = s3;
    }
    __syncthreads();
    bf16x8 af[4], bfr[4];
    for (int mi = 0; mi < 4; ++mi)
      af[mi] = *(const bf16x8*)(a_lds + (mi*16 + lr)*40 + g*8);
    for (int nj = 0; nj < 4; ++nj)
      bfr[nj] = *(const bf16x8*)(b_lds + (w*64 + nj*16 + lr)*40 + g*8);
    for (int mi = 0; mi < 4; ++mi)
      for (int nj = 0; nj < 4; ++nj)
        acc[mi][nj] = __builtin_amdgcn_mfma_f32_16x16x32_bf16(af[mi], bfr[nj], acc[mi][nj], 0, 0, 0);
  }

  for (int mi = 0; mi < 4; ++mi)
    for (int nj = 0; nj < 4; ++nj)
      for (int p = 0; p < 4; ++p){
        int re = mi*16 + g*4 + p;
        int n = n0 + re;
        if (n < NN)
          pre[(size_t)n*512 + half*256 + w*64 + nj*16 + lr] = f2bf(acc[mi][nj][p]);
      }
}

// ---- fused edge kernel: 8 waves, wave-private gl_lds staging, barrier-free k-loop,
//      ballot-mask uniform segmented reduce (measured-best r10 configuration) ----
__launch_bounds__(512, 4)
__global__ void edge_msg_k(const int2* __restrict__ smeta,
                           const u16* __restrict__ pre,
                           const float* __restrict__ prebg,
                           const u16* __restrict__ w2img,
                           const float* __restrict__ b2g,
                           const float* __restrict__ gate_tab,
                           float* __restrict__ h,
                           int layer){
  __shared__ u16 b_lds[16384];     // 32KB: 2 bufs x 8 waves x (32 cols x 32 k); reused for msgs
  __shared__ u16 t_lds[64*264];    // 33792B
  __shared__ int   row_l[64];
  __shared__ float gate_l[64];
  __shared__ u64   mask_l;

  const int tid = threadIdx.x;
  // bijective XCD-chunked swizzle: 5000 = 8 * 625
  const int bid = blockIdx.x;
  const int blk = (bid & 7)*625 + (bid >> 3);
  const int eBase = blk * 64;
  const int w = tid >> 6, lane = tid & 63, g = lane >> 4, lr = lane & 15;
  const int rstage = tid >> 3, q = tid & 7;

  const size_t wbase = (size_t)layer*65536;

  // prologue: stage W2 k-steps 0,1 (wave-private 32-col slices)
  #pragma unroll
  for (int b = 0; b < 2; ++b)
    #pragma unroll
    for (int j = 0; j < 2; ++j)
      gl_lds16(w2img + wbase + (size_t)(b*256 + w*32 + j*16)*32 + lane*8,
               b_lds + b*8192 + w*1024 + j*512);

  // one-load edge metadata
  int2 m0 = smeta[eBase + rstage];
  const int rI  = m0.x & 0xFFFFF;
  const int btI = (m0.x >> 20) & 7;
  const int cI  = m0.y;

  if (tid < 64){
    int2 mm = smeta[eBase + tid];
    int r = mm.x & 0xFFFFF;
    row_l[tid] = r;
    gate_l[tid] = gate_tab[layer*5 + ((mm.x >> 20) & 7)];
    int rprev = __shfl_up(r, 1);
    bool fl = (tid > 0) && (r != rprev);
    u64 mk = __ballot(fl);
    if (tid == 0) mask_l = mk;
  }

  // ---- t = relu(pre1[row] + pre2[col] + preb[bt]) -> bf16 t_lds ----
  {
    const u16* p1 = pre + (size_t)rI*512;
    const u16* p2 = pre + (size_t)cI*512 + 256;
    const float* pb = prebg + (size_t)(layer*5 + btI)*256;
    uint4 v1[4], v2[4];
    #pragma unroll
    for (int it = 0; it < 4; ++it){
      int c0 = it*64 + q*8;
      v1[it] = *(const uint4*)(p1 + c0);
      v2[it] = *(const uint4*)(p2 + c0);
    }
    #pragma unroll
    for (int it = 0; it < 4; ++it){
      int c0 = it*64 + q*8;
      float4 pa = *(const float4*)(pb + c0);
      float4 pc = *(const float4*)(pb + c0 + 4);
      uint4 ov;
      ov.x = relu_pack(v1[it].x, v2[it].x, pa.x, pa.y);
      ov.y = relu_pack(v1[it].y, v2[it].y, pa.z, pa.w);
      ov.z = relu_pack(v1[it].z, v2[it].z, pc.x, pc.y);
      ov.w = relu_pack(v1[it].w, v2[it].w, pc.z, pc.w);
      *(uint4*)(t_lds + rstage*264 + c0) = ov;
    }
  }

  __syncthreads();   // t_lds + row_l/gate_l/mask_l visible to all waves

  f32x4 acc[4][2];
  for (int mi = 0; mi < 4; ++mi)
    for (int nj = 0; nj < 2; ++nj)
      acc[mi][nj] = (f32x4){0.f,0.f,0.f,0.f};

  const int sw = (g ^ ((lr >> 1) & 3)) << 3;

  // ---- GEMM2: barrier-free, wave-private double-buffered staging ----
  #pragma unroll
  for (int ks = 0; ks < 8; ++ks){
    if (ks >= 1 && ks < 7){
      #pragma unroll
      for (int j = 0; j < 2; ++j)
        gl_lds16(w2img + wbase + (size_t)((ks+1)*256 + w*32 + j*16)*32 + lane*8,
                 b_lds + ((ks+1)&1)*8192 + w*1024 + j*512);
      asm volatile("s_waitcnt vmcnt(2)" ::: "memory");
    } else if (ks == 0){
      asm volatile("s_waitcnt vmcnt(2)" ::: "memory");
    } else {
      asm volatile("s_waitcnt vmcnt(0)" ::: "memory");
    }
    const u16* bb = b_lds + (ks&1)*8192 + w*1024;
    bf16x8 af[4], bfr[2];
    for (int nj = 0; nj < 2; ++nj)
      bfr[nj] = *(const bf16x8*)(bb + (nj*16 + lr)*32 + sw);
    for (int mi = 0; mi < 4; ++mi)
      af[mi] = *(const bf16x8*)(t_lds + (mi*16 + lr)*264 + ks*32 + g*8);
    __builtin_amdgcn_s_setprio(1);
    for (int mi = 0; mi < 4; ++mi)
      for (int nj = 0; nj < 2; ++nj)
        acc[mi][nj] = __builtin_amdgcn_mfma_f32_16x16x32_bf16(af[mi], bfr[nj], acc[mi][nj], 0, 0, 0);
    __builtin_amdgcn_s_setprio(0);
  }

  // ---- epilogue: (+b2)*gate -> bf16 msgs, wave-private b_lds, b64 stores ----
  {
    float b2v[2];
    for (int nj = 0; nj < 2; ++nj) b2v[nj] = b2g[layer*HD + w*32 + nj*16 + lr];
    for (int mi = 0; mi < 4; ++mi)
      for (int nj = 0; nj < 2; ++nj){
        u16* mb = b_lds + nj*8192 + w*1024 + lr*64;
        float v[4];
        #pragma unroll
        for (int p = 0; p < 4; ++p){
          int re = mi*16 + g*4 + p;
          v[p] = (acc[mi][nj][p] + b2v[nj]) * gate_l[re];
        }
        int slot = (mi*2 + (g >> 1)) ^ (lr & 7);
        uint2 pkv; pkv.x = pk2t(v[0], v[1]); pkv.y = pk2t(v[2], v[3]);
        *(uint2*)(mb + slot*8 + (g & 1)*4) = pkv;
      }
  }
  __syncthreads();

  // ---- segmented reduction: wave-uniform mask flush (no per-element compare) ----
  {
    const int cl = tid & 255, half = tid >> 8;   // half uniform per wave
    u64 mk = mask_l;
    u32 m32 = (u32)(mk >> (half ? 32 : 0));
    m32 = __builtin_amdgcn_readfirstlane(m32);
    const u16* mb = b_lds + ((cl >> 4) & 1)*8192 + (cl >> 5)*1024 + (cl & 15)*64;
    float run = 0.f;
    #pragma unroll
    for (int e8l = 0; e8l < 4; ++e8l){
      int e8 = half*4 + e8l;
      bf16x8 mv = *(const bf16x8*)(mb + ((e8 ^ (cl & 7)) << 3));
      #pragma unroll
      for (int j = 0; j < 8; ++j){
        int el = e8l*8 + j;              // local edge 0..31
        run += bf2f((u16)mv[j]);
        bool fl = (el == 31) || ((m32 >> (el + 1)) & 1u);
        if (fl){
          int rr = row_l[half*32 + el];
          atomicAdd(h + (size_t)rr*HD + cl, run);
          run = 0.f;
        }
      }
    }
  }
}

// ---- column sums for pooling ----
__global__ void pool_k(const float* __restrict__ h,
                       float* __restrict__ pooled){
  int c = threadIdx.x;
  int r0 = blockIdx.x * 50;
  float s = 0.f;
  for (int r = r0; r < r0 + 50; ++r)
    s += h[(size_t)r*HD + c];
  atomicAdd(&pooled[c], s);
}

// ---- fg = mean(h) @ fg_w + fg_b (computed once) ----
__global__ void fg_k(const float* __restrict__ pooled,
                     const float* __restrict__ fg_w,
                     const float* __restrict__ fg_b,
                     float* __restrict__ fg_vals){
  int o = threadIdx.x;
  int k = o >> 4, j = o & 15;
  float s = 0.f;
  for (int d = 0; d < HD; ++d) s += pooled[d] * fg_w[(size_t)k*HD*16 + d*16 + j];
  fg_vals[o] = s / (float)NN + fg_b[k*16 + j];
}

__global__ void bcast_fg_k(const float* __restrict__ fg_vals,
                           float* __restrict__ out_fg){
  __shared__ float fv[64];
  if (threadIdx.x < 64) fv[threadIdx.x] = fg_vals[threadIdx.x];
  __syncthreads();
  int i = blockIdx.x*256 + threadIdx.x;
  out_fg[i] = fv[i & 63];
}

// ---- chemical properties MLP, both layers via MFMA ----
__launch_bounds__(256, 3)
__global__ void props_mfma_k(const float* __restrict__ h,
                             const u16* __restrict__ pw1bf,
                             const float* __restrict__ pb1,
                             const u16* __restrict__ pw2bf,
                             const float* __restrict__ pb2,
                             float* __restrict__ outp){
  __shared__ u16 a_lds[64*40];
  __shared__ u16 b2_lds[128*40];   // k-loop W1 staging; then pw2 [32][k128] stride 136
  __shared__ u16 t2[64*136];
  const int tid = threadIdx.x;
  const int n0 = blockIdx.x*64;
  const int w = tid >> 6, lane = tid & 63, g = lane >> 4, lr = lane & 15;
  const int rstage = tid >> 2, q = tid & 3;
  int arow = n0 + rstage; if (arow >= NN) arow = NN-1;
  const float* hrow = h + (size_t)arow*HD;

  const int colb = tid >> 1, halfb = tid & 1;

  f32x4 acc[4][2];
  for (int mi = 0; mi < 4; ++mi)
    for (int nj = 0; nj < 2; ++nj)
      acc[mi][nj] = (f32x4){0.f,0.f,0.f,0.f};

  for (int ks = 0; ks < 8; ++ks){
    __syncthreads();
    {
      const float* src = hrow + ks*32 + q*8;
      float4 f0 = *(const float4*)src;
      float4 f1 = *(const float4*)(src + 4);
      uint4 av;
      av.x = pk2(f0.x,f0.y); av.y = pk2(f0.z,f0.w);
      av.z = pk2(f1.x,f1.y); av.w = pk2(f1.z,f1.w);
      *(uint4*)(a_lds + rstage*40 + q*8) = av;
    }
    {
      const u16* src = pw1bf + colb*256 + ks*32 + halfb*16;
      uint4 s0 = *(const uint4*)src;
      uint4 s1 = *(const uint4*)(src + 8);
      u16* dst = b2_lds + colb*40 + halfb*16;
      *(uint4*)dst = s0; *(uint4*)(dst + 8) = s1;
    }
    __syncthreads();
    bf16x8 af[4], bfr[2];
    for (int mi = 0; mi < 4; ++mi)
      af[mi] = *(const bf16x8*)(a_lds + (mi*16 + lr)*40 + g*8);
    for (int nj = 0; nj < 2; ++nj)
      bfr[nj] = *(const bf16x8*)(b2_lds + (w*32 + nj*16 + lr)*40 + g*8);
    for (int mi = 0; mi < 4; ++mi)
      for (int nj = 0; nj < 2; ++nj)
        acc[mi][nj] = __builtin_amdgcn_mfma_f32_16x16x32_bf16(af[mi], bfr[nj], acc[mi][nj], 0, 0, 0);
  }

  // bias + relu -> t2 (bf16)
  {
    float b1v[2];
    for (int nj = 0; nj < 2; ++nj) b1v[nj] = pb1[w*32 + nj*16 + lr];
    for (int mi = 0; mi < 4; ++mi)
      for (int nj = 0; nj < 2; ++nj){
        int colt = w*32 + nj*16 + lr;
        for (int p = 0; p < 4; ++p){
          float v = acc[mi][nj][p] + b1v[nj];
          v = v > 0.f ? v : 0.f;
          t2[(mi*16 + g*4 + p)*136 + colt] = f2bf(v);
        }
      }
  }
  __syncthreads();   // t2 complete; b2_lds reads from k-loop done

  // stage pw2bf [32 cols][128 k] into b2_lds at stride 136
  {
    int col = tid >> 3, part = tid & 7;
    const u16* src = pw2bf + col*128 + part*16;
    u16* dst = b2_lds + col*136 + part*16;
    *(uint4*)dst       = *(const uint4*)src;
    *(uint4*)(dst + 8) = *(const uint4*)(src + 8);
  }
  __syncthreads();

  // phase 2 via MFMA: [64x128] @ [128x32]; wave w owns rows w*16..w*16+15
  {
    f32x4 acc2[2];
    for (int nj = 0; nj < 2; ++nj) acc2[nj] = (f32x4){0.f,0.f,0.f,0.f};
    for (int ks = 0; ks < 4; ++ks){
      bf16x8 af = *(const bf16x8*)(t2 + (w*16 + lr)*136 + ks*32 + g*8);
      for (int nj = 0; nj < 2; ++nj){
        bf16x8 bf = *(const bf16x8*)(b2_lds + (nj*16 + lr)*136 + ks*32 + g*8);
        acc2[nj] = __builtin_amdgcn_mfma_f32_16x16x32_bf16(af, bf, acc2[nj], 0, 0, 0);
      }
    }
    for (int nj = 0; nj < 2; ++nj)
      for (int p = 0; p < 4; ++p){
        int n = n0 + w*16 + g*4 + p;
        int col = nj*16 + lr;
        if (n < NN)
          outp[(size_t)n*32 + col] = acc2[nj][p] + pb2[col];
      }
  }
}

extern "C" void kernel_launch(void* const* d_in, const int* in_sizes, int n_in,
                              void* d_out, int out_size, void* d_ws, size_t ws_size,
                              hipStream_t stream) {
  const float* x            = (const float*)d_in[0];
  const int*   eidx         = (const int*)  d_in[1];
  const float* eattr        = (const float*)d_in[2];
  const float* atom_table   = (const float*)d_in[4];
  const float* charge_table = (const float*)d_in[5];
  const float* hybrid_table = (const float*)d_in[6];
  const float* bond_table   = (const float*)d_in[7];
  const float* gw1          = (const float*)d_in[8];
  const float* gb1          = (const float*)d_in[9];
  const float* gw2          = (const float*)d_in[10];
  const float* gb2          = (const float*)d_in[11];
  const float* attw         = (const float*)d_in[12];
  const float* attb         = (const float*)d_in[13];
  const float* pw1          = (const float*)d_in[14];
  const float* pb1          = (const float*)d_in[15];
  const float* pw2          = (const float*)d_in[16];
  const float* pb2          = (const float*)d_in[17];
  const float* fgw          = (const float*)d_in[18];
  const float* fgb          = (const float*)d_in[19];

  float* out       = (float*)d_out;
  float* out_h     = out;
  float* out_props = out + (size_t)NN*HD;
  float* out_fg    = out_props + (size_t)NN*32;
  float* out_at    = out_fg + (size_t)NN*64;

  char* ws = (char*)d_ws;
  u16*   pre      = (u16*)  (ws + WS_PRE);
  u16*   w1t      = (u16*)  (ws + WS_W1T);
  u16*   w2img    = (u16*)  (ws + WS_W2I);
  u16*   pw1bf    = (u16*)  (ws + WS_PW1);
  u16*   pw2bf    = (u16*)  (ws + WS_PW2);
  float* prebg    = (float*)(ws + WS_PREB);
  float* gate_tab = (float*)(ws + WS_GATE);
  float* pooled   = (float*)(ws + WS_POOL);
  float* fg_vals  = (float*)(ws + WS_FGV);
  int*   cnt      = (int*)  (ws + WS_CNT);
  int2*  smeta    = (int2*) (ws + WS_META);

  setup_k<<<5235, 256, 0, stream>>>(gw1, gw2, pw1, pw2, bond_table, gb1, attw, attb,
                                    x, atom_table, charge_table, hybrid_table,
                                    w1t, w2img, pw1bf, pw2bf, prebg, gate_tab, pooled,
                                    cnt, out_h, out_at);

  hist_k<<<1250, 256, 0, stream>>>(eidx, cnt);
  scan_k<<<1, 1024, 0, stream>>>(cnt);
  scatter_k<<<1250, 256, 0, stream>>>(eidx, eattr, cnt, smeta);

  for (int l = 0; l < 3; ++l){
    pre_k<<<dim3(313, 2), 256, 0, stream>>>(out_h, w1t, pre, l);
    edge_msg_k<<<5000, 512, 0, stream>>>(smeta, pre, prebg, w2img,
                                         gb2, gate_tab, out_h, l);
  }

  pool_k<<<400, 256, 0, stream>>>(out_h, pooled);
  fg_k<<<1, 64, 0, stream>>>(pooled, fgw, fgb, fg_vals);
  props_mfma_k<<<313, 256, 0, stream>>>(out_h, pw1bf, pb1, pw2bf, pb2, out_props);
  bcast_fg_k<<<5000, 256, 0, stream>>>(fg_vals, out_fg);
}